// Round 1
// baseline (295.261 us; speedup 1.0000x reference)
//
#include <hip/hip_runtime.h>
#include <math.h>

// Problem constants
#define BATCH   16384
#define XDIM    18        // IN_FEATURES + 1 + LATENT
#define LATENT  16
#define NM      128       // (IN_FEATURES+1)*OUT_FEATURES
#define KDIM    4096      // COEFFS_SIZE
#define OUTF    64
#define KB      32        // N_EIG * N_HARMONICS

// Tiling for the fused main kernel
#define BM 32
#define BK 64

// ---------------------------------------------------------------------------
// Kernel A: W_effT[j][m] = sum_k basis[k] * fc2_w[(m*32+k)*4096 + j]   (4096 x 128)
//           b_eff[m]    = sum_k basis[k] * fc2_b[m*32+k]               (128)
// basis[k] = k<16 ? cos(arg*n[k]) : sin(arg*n[k-16]),  n[i]=16*i/15, arg=s*dil+shift
// ---------------------------------------------------------------------------
__global__ __launch_bounds__(256) void precompute_kernel(
    const float* __restrict__ x, const float* __restrict__ fc2_w,
    const float* __restrict__ fc2_b, const float* __restrict__ dil,
    const float* __restrict__ shf, float* __restrict__ weffT,
    float* __restrict__ beff)
{
    __shared__ float basis[KB];
    const int tid = threadIdx.x;
    if (tid < KB) {
        const float s   = x[(size_t)(BATCH - 1) * XDIM + 1];  // x[-1, IN_FEATURES]
        const float arg = s * dil[0] + shf[0];
        const int   hh  = tid & 15;
        const float n   = 16.0f * (float)hh / 15.0f;          // linspace(0,16,16)
        const float a   = arg * n;
        basis[tid] = (tid < 16) ? cosf(a) : sinf(a);
    }
    __syncthreads();

    const int bid = blockIdx.x;
    if (bid < 2048) {
        const int idx = bid * 256 + tid;   // idx = m*4096 + j
        const int m   = idx >> 12;
        const int j   = idx & 4095;
        const float* src = fc2_w + (size_t)m * KB * KDIM + j;
        float acc = 0.0f;
        #pragma unroll
        for (int k = 0; k < KB; ++k)
            acc = fmaf(basis[k], src[(size_t)k * KDIM], acc);
        weffT[(size_t)j * NM + m] = acc;   // K-major layout for coalesced staging
    } else if (tid < NM) {
        float acc = 0.0f;
        #pragma unroll
        for (int k = 0; k < KB; ++k)
            acc = fmaf(basis[k], fc2_b[tid * KB + k], acc);
        beff[tid] = acc;
    }
}

// ---------------------------------------------------------------------------
// Kernel B: fused  h = relu(z @ fc1_w^T + fc1_b)  (on the fly, tiled over K)
//                  w = h @ W_effT + b_eff          (M=16384, N=128, K=4096)
//                  out[b,o] = x[b,0]*w[b,o] + w[b,64+o]
// Block: 256 threads, BM=32 rows, per-thread 4x4 f32 register tile.
// ---------------------------------------------------------------------------
__global__ __launch_bounds__(256) void fused_kernel(
    const float* __restrict__ x, const float* __restrict__ fc1_w,
    const float* __restrict__ fc1_b, const float* __restrict__ weffT,
    const float* __restrict__ beff, float* __restrict__ out)
{
    __shared__ float zs[BM][LATENT];    // 2 KB
    __shared__ float hs[BM][BK + 1];    // +1 pad: breaks same-bank on hs[r][kk] reads
    __shared__ float wt[BK][NM];        // 32 KB; reused as wl[BM][NM] in epilogue

    const int tid  = threadIdx.x;
    const int row0 = blockIdx.x * BM;

    // stage z rows for this block (scalar; x rows are 18 floats, unaligned for float4)
    for (int idx = tid; idx < BM * LATENT; idx += 256) {
        const int r = idx >> 4, l = idx & 15;
        zs[r][l] = x[(size_t)(row0 + r) * XDIM + 2 + l];   // z = x[:, -16:]
    }

    const int tc = tid & 31;   // col group: cols tc*4 .. tc*4+3
    const int tr = tid >> 5;   // row group: rows tr*4 .. tr*4+3 (0..7)
    const int jj = tid & 63;   // h-phase: j within K-tile
    const int rg = tid >> 6;   // h-phase: row octet 0..3

    float acc[4][4] = {};

    for (int kt = 0; kt < KDIM / BK; ++kt) {
        const int k0 = kt * BK;
        __syncthreads();   // zs ready (first iter) / previous MAC phase done

        // ---- h phase: each thread computes h for one j, 8 rows ----
        {
            const int j = k0 + jj;
            float fw[16];
            const float4* fw4 = reinterpret_cast<const float4*>(fc1_w + (size_t)j * 16);
            #pragma unroll
            for (int q = 0; q < 4; ++q) {
                const float4 v = fw4[q];
                fw[4*q+0] = v.x; fw[4*q+1] = v.y; fw[4*q+2] = v.z; fw[4*q+3] = v.w;
            }
            const float fb = fc1_b[j];
            #pragma unroll
            for (int r8 = 0; r8 < 8; ++r8) {
                const int r = rg * 8 + r8;
                float h = fb;
                #pragma unroll
                for (int l = 0; l < LATENT; ++l)
                    h = fmaf(zs[r][l], fw[l], h);
                hs[r][jj] = fmaxf(h, 0.0f);
            }
        }

        // ---- stage W_effT tile: rows k0..k0+63, 128 floats each (coalesced) ----
        {
            const float4* src = reinterpret_cast<const float4*>(weffT + (size_t)k0 * NM);
            float4* dst = reinterpret_cast<float4*>(&wt[0][0]);
            #pragma unroll
            for (int i = 0; i < 8; ++i)
                dst[i * 256 + tid] = src[i * 256 + tid];
        }
        __syncthreads();

        // ---- MAC phase ----
        #pragma unroll 4
        for (int kk = 0; kk < BK; ++kk) {
            const float4 wv = *reinterpret_cast<const float4*>(&wt[kk][tc * 4]);
            float hv[4];
            #pragma unroll
            for (int i = 0; i < 4; ++i) hv[i] = hs[tr * 4 + i][kk];
            #pragma unroll
            for (int i = 0; i < 4; ++i) {
                acc[i][0] = fmaf(hv[i], wv.x, acc[i][0]);
                acc[i][1] = fmaf(hv[i], wv.y, acc[i][1]);
                acc[i][2] = fmaf(hv[i], wv.z, acc[i][2]);
                acc[i][3] = fmaf(hv[i], wv.w, acc[i][3]);
            }
        }
    }

    __syncthreads();   // last MAC reads of wt done; reuse wt as wl[BM][NM]

    // ---- write w + b_eff into LDS so each thread can pair cols (o, o+64) ----
    {
        float* wl = &wt[0][0];
        float be[4];
        #pragma unroll
        for (int c = 0; c < 4; ++c) be[c] = beff[tc * 4 + c];
        #pragma unroll
        for (int i = 0; i < 4; ++i) {
            #pragma unroll
            for (int c = 0; c < 4; ++c)
                wl[(tr * 4 + i) * NM + tc * 4 + c] = acc[i][c] + be[c];
        }
    }
    __syncthreads();

    // ---- epilogue: out[b,o] = inp[b] * w[b,o] + w[b,64+o] ----
    {
        const float* wl = &wt[0][0];
        const int o   = tid & 63;
        const int rg2 = tid >> 6;
        #pragma unroll
        for (int i = 0; i < 8; ++i) {
            const int r = rg2 * 8 + i;
            const float inp = x[(size_t)(row0 + r) * XDIM];   // x[:, 0]
            out[(size_t)(row0 + r) * OUTF + o] = fmaf(inp, wl[r * NM + o], wl[r * NM + OUTF + o]);
        }
    }
}

// ---------------------------------------------------------------------------
extern "C" void kernel_launch(void* const* d_in, const int* in_sizes, int n_in,
                              void* d_out, int out_size, void* d_ws, size_t ws_size,
                              hipStream_t stream) {
    const float* x     = (const float*)d_in[0];
    const float* fc1_w = (const float*)d_in[1];
    const float* fc1_b = (const float*)d_in[2];
    const float* fc2_w = (const float*)d_in[3];
    const float* fc2_b = (const float*)d_in[4];
    const float* dil   = (const float*)d_in[5];
    const float* shf   = (const float*)d_in[6];
    float* out = (float*)d_out;

    // workspace: W_effT (4096*128 f32 = 2 MB) + b_eff (128 f32)
    float* weffT = (float*)d_ws;
    float* beff  = weffT + (size_t)KDIM * NM;

    precompute_kernel<<<2049, 256, 0, stream>>>(x, fc2_w, fc2_b, dil, shf, weffT, beff);
    fused_kernel<<<BATCH / BM, 256, 0, stream>>>(x, fc1_w, fc1_b, weffT, beff, out);
}

// Round 2
// 79.037 us; speedup vs baseline: 3.7357x; 3.7357x over previous
//
#include <hip/hip_runtime.h>
#include <math.h>

#define BATCH  16384
#define XDIM   18
#define LATENT 16
#define NM     128
#define KDIM   4096
#define OUTF   64
#define KB     32

typedef short s16x8 __attribute__((ext_vector_type(8)));
typedef float f32x16 __attribute__((ext_vector_type(16)));

__device__ __forceinline__ unsigned short f2bf(float f) {
    union { float f; unsigned u; } v; v.f = f;
    return (unsigned short)((v.u + 0x7FFFu + ((v.u >> 16) & 1u)) >> 16);
}

// ---------------------------------------------------------------------------
// Precompute: W_eff/fc1_w into MFMA-fragment-layout bf16 buffers + b_eff.
//   blocks 0..511   : (m = b>>2, kq = b&3) -> W_eff frags for 1024 k values
//   blocks 512..575 : fc1_w A-frags (8192 lane-slots of 16B)
// Frag conventions (32x32x16): A: lane l holds A[l&31][(l>>5)*8 + r]
//                              B: lane l holds B[(l>>5)*8 + r][l&31]
// wfrag layout: [kc 0..255][ct 0..3][lane 0..63][8 bf16]
// f1frag layout: [jt 0..127][lane 0..63][8 bf16]
// ---------------------------------------------------------------------------
__global__ __launch_bounds__(128) void precompute_kernel(
    const float* __restrict__ x, const float* __restrict__ fc1_w,
    const float* __restrict__ fc2_w, const float* __restrict__ fc2_b,
    const float* __restrict__ dil, const float* __restrict__ shf,
    unsigned short* __restrict__ wfrag, unsigned short* __restrict__ f1frag,
    float* __restrict__ beff)
{
    const int tid = threadIdx.x;
    const int bid = blockIdx.x;
    if (bid < 512) {
        __shared__ float basis[KB];
        __shared__ float bred[32];
        if (tid < KB) {
            const float s   = x[(size_t)(BATCH - 1) * XDIM + 1];
            const float arg = s * dil[0] + shf[0];
            const float n   = 16.0f * (float)(tid & 15) / 15.0f;
            const float a   = arg * n;
            basis[tid] = (tid < 16) ? cosf(a) : sinf(a);
        }
        __syncthreads();
        const int m  = bid >> 2, kq = bid & 3;
        const int k8 = kq * 128 + tid;        // k-octet 0..511
        const int k  = k8 * 8;
        float acc[8] = {0.f,0.f,0.f,0.f,0.f,0.f,0.f,0.f};
        const float* src = fc2_w + (size_t)m * KB * KDIM + k;
        #pragma unroll 4
        for (int kb = 0; kb < KB; ++kb) {
            const float wgt = basis[kb];
            const float4 a = *(const float4*)(src + (size_t)kb * KDIM);
            const float4 b = *(const float4*)(src + (size_t)kb * KDIM + 4);
            acc[0] = fmaf(wgt, a.x, acc[0]); acc[1] = fmaf(wgt, a.y, acc[1]);
            acc[2] = fmaf(wgt, a.z, acc[2]); acc[3] = fmaf(wgt, a.w, acc[3]);
            acc[4] = fmaf(wgt, b.x, acc[4]); acc[5] = fmaf(wgt, b.y, acc[5]);
            acc[6] = fmaf(wgt, b.z, acc[6]); acc[7] = fmaf(wgt, b.w, acc[7]);
        }
        const int ct = m >> 5, coln = m & 31;
        const int kc = k8 >> 1, kg = k8 & 1;
        const int lane = kg * 32 + coln;
        unsigned short t[8];
        #pragma unroll
        for (int i = 0; i < 8; ++i) t[i] = f2bf(acc[i]);
        *(uint4*)(wfrag + ((size_t)(kc * 4 + ct) * 64 + lane) * 8) = *(const uint4*)t;
        if (kq == 0 && tid < 32) bred[tid] = basis[tid] * fc2_b[m * KB + tid];
        __syncthreads();
        if (kq == 0 && tid == 0) {
            float s = 0.f;
            #pragma unroll
            for (int i = 0; i < 32; ++i) s += bred[i];
            beff[m] = s;
        }
    } else {
        const int slot = (bid - 512) * 128 + tid;   // 0..8191
        const int lane = slot & 63;
        const int jt   = slot >> 6;
        const int j    = jt * 32 + (lane & 31);
        const int kg   = lane >> 5;
        const float* src = fc1_w + (size_t)j * LATENT + kg * 8;
        const float4 a = *(const float4*)(src);
        const float4 b = *(const float4*)(src + 4);
        unsigned short t[8];
        t[0]=f2bf(a.x); t[1]=f2bf(a.y); t[2]=f2bf(a.z); t[3]=f2bf(a.w);
        t[4]=f2bf(b.x); t[5]=f2bf(b.y); t[6]=f2bf(b.z); t[7]=f2bf(b.w);
        *(uint4*)(f1frag + (size_t)slot * 8) = *(const uint4*)t;
    }
}

// ---------------------------------------------------------------------------
// Fused: per block 64 rows. 8 waves. Per K-step (BK=64):
//  - stage 16KB W_eff frags (issue early, write late)
//  - waves 0-3: hT = mfma(fc1w_frag, z_frag) [M=32 j, N=32 rows, K=16]
//    + bias + relu -> bf16 -> hs[64][72] (stride 144B, conflict-free b128)
//  - all waves: 4x mfma(h_frag, weff_frag) into 32x32 acc tile
// Epilogue: acc + beff -> LDS wfull[64][128] -> out = inp*w[:, :64] + w[:,64:]
// ---------------------------------------------------------------------------
__global__ __launch_bounds__(512) void fused_kernel(
    const float* __restrict__ x, const float* __restrict__ fc1_b,
    const unsigned short* __restrict__ wfrag,
    const unsigned short* __restrict__ f1frag,
    const float* __restrict__ beff, float* __restrict__ out)
{
    __shared__ __align__(16) char smem[64 * 128 * 4];       // 32 KB
    unsigned short* wlds = (unsigned short*)smem;           // 8192 us = 16 KB
    unsigned short* hs   = (unsigned short*)smem + 8192;    // 64*72 us = 9 KB
    float* wfull = (float*)smem;

    const int tid  = threadIdx.x;
    const int w    = tid >> 6, l = tid & 63;
    const int l31  = l & 31,  lg = l >> 5;
    const int row0 = blockIdx.x * 64;
    const int rt   = w >> 2,  ct = w & 3;          // main: 32x32 tile (rt, ct)
    const int jt_h = w >> 1,  rt_h = w & 1;        // hT phase (waves 0-3)

    // z B-frag: lane l holds z[rt_h*32 + l31][lg*8 + r], r=0..7  (loop-invariant)
    s16x8 zfrag;
    #pragma unroll
    for (int i = 0; i < 8; ++i) zfrag[i] = 0;
    if (w < 4) {
        const float* zp = x + (size_t)(row0 + rt_h * 32 + l31) * XDIM + 2 + lg * 8;
        #pragma unroll
        for (int q = 0; q < 4; ++q) {
            const float2 t = *(const float2*)(zp + q * 2);
            zfrag[2 * q]     = (short)f2bf(t.x);
            zfrag[2 * q + 1] = (short)f2bf(t.y);
        }
    }

    f32x16 acc;
    #pragma unroll
    for (int i = 0; i < 16; ++i) acc[i] = 0.0f;

    for (int step = 0; step < 64; ++step) {
        const int k0 = step * 64;
        // issue staging loads early (16 KB of W_eff frags for this K-step)
        const uint4* gsrc = (const uint4*)(wfrag + (size_t)step * 8192);
        const uint4 st0 = gsrc[tid];
        const uint4 st1 = gsrc[tid + 512];

        // hT phase: waves 0-3
        if (w < 4) {
            const uint4 fv = *(const uint4*)(f1frag + ((size_t)(step * 2 + jt_h) * 64 + l) * 8);
            s16x8 afrag;
            #pragma unroll
            for (int i = 0; i < 4; ++i) {
                const unsigned u = ((const unsigned*)&fv)[i];
                afrag[2 * i]     = (short)(u & 0xFFFF);
                afrag[2 * i + 1] = (short)(u >> 16);
            }
            f32x16 hacc;
            #pragma unroll
            for (int i = 0; i < 16; ++i) hacc[i] = 0.0f;
            hacc = __builtin_amdgcn_mfma_f32_32x32x16_bf16(afrag, zfrag, hacc, 0, 0, 0);
            // C layout: col = l&31 (row_batch), row = (r&3)+8*(r>>2)+4*lg (j_local)
            const float* bp = fc1_b + k0 + jt_h * 32 + 4 * lg;
            unsigned short* hrow = hs + (size_t)(rt_h * 32 + l31) * 72 + jt_h * 32 + 4 * lg;
            #pragma unroll
            for (int g = 0; g < 4; ++g) {
                const float4 bb = *(const float4*)(bp + 8 * g);
                const unsigned short t0 = f2bf(fmaxf(hacc[g * 4 + 0] + bb.x, 0.f));
                const unsigned short t1 = f2bf(fmaxf(hacc[g * 4 + 1] + bb.y, 0.f));
                const unsigned short t2 = f2bf(fmaxf(hacc[g * 4 + 2] + bb.z, 0.f));
                const unsigned short t3 = f2bf(fmaxf(hacc[g * 4 + 3] + bb.w, 0.f));
                uint2 u;
                u.x = (unsigned)t0 | ((unsigned)t1 << 16);
                u.y = (unsigned)t2 | ((unsigned)t3 << 16);
                *(uint2*)(hrow + 8 * g) = u;
            }
        }

        // write staged W_eff frags
        ((uint4*)wlds)[tid]       = st0;
        ((uint4*)wlds)[tid + 512] = st1;
        __syncthreads();

        // main MFMAs: A = h[rt*32 + l31][kc*16 + lg*8 + r], B = weff frag
        const unsigned short* arow  = hs + (size_t)(rt * 32 + l31) * 72 + lg * 8;
        const unsigned short* bbase = wlds + (size_t)ct * 512 + l * 8;
        #pragma unroll
        for (int kc = 0; kc < 4; ++kc) {
            const s16x8 a = *(const s16x8*)(arow + kc * 16);
            const s16x8 b = *(const s16x8*)(bbase + kc * 2048);
            acc = __builtin_amdgcn_mfma_f32_32x32x16_bf16(a, b, acc, 0, 0, 0);
        }
        __syncthreads();
    }

    // epilogue: acc -> wfull (f32) with b_eff added
    const float be = beff[ct * 32 + l31];
    #pragma unroll
    for (int r = 0; r < 16; ++r) {
        const int rowl = (r & 3) + 8 * (r >> 2) + 4 * lg;
        wfull[(size_t)(rt * 32 + rowl) * NM + ct * 32 + l31] = acc[r] + be;
    }
    __syncthreads();

    {
        const int o = tid & 63, rg = tid >> 6;
        #pragma unroll
        for (int i = 0; i < 8; ++i) {
            const int r = rg * 8 + i;
            const float inp = x[(size_t)(row0 + r) * XDIM];
            out[(size_t)(row0 + r) * OUTF + o] =
                fmaf(inp, wfull[r * NM + o], wfull[r * NM + OUTF + o]);
        }
    }
}

// ---------------------------------------------------------------------------
extern "C" void kernel_launch(void* const* d_in, const int* in_sizes, int n_in,
                              void* d_out, int out_size, void* d_ws, size_t ws_size,
                              hipStream_t stream) {
    const float* x     = (const float*)d_in[0];
    const float* fc1_w = (const float*)d_in[1];
    const float* fc1_b = (const float*)d_in[2];
    const float* fc2_w = (const float*)d_in[3];
    const float* fc2_b = (const float*)d_in[4];
    const float* dil   = (const float*)d_in[5];
    const float* shf   = (const float*)d_in[6];
    float* out = (float*)d_out;

    // workspace: wfrag 1MB (524288 us) + f1frag 128KB (65536 us) + beff 512B
    unsigned short* wfrag  = (unsigned short*)d_ws;
    unsigned short* f1frag = wfrag + 524288;
    float*          beff   = (float*)(f1frag + 65536);

    precompute_kernel<<<576, 128, 0, stream>>>(x, fc1_w, fc2_w, fc2_b, dil, shf,
                                               wfrag, f1frag, beff);
    fused_kernel<<<BATCH / 64, 512, 0, stream>>>(x, fc1_b, wfrag, f1frag, beff, out);
}

// Round 3
// 78.426 us; speedup vs baseline: 3.7648x; 1.0078x over previous
//
#include <hip/hip_runtime.h>
#include <math.h>

#define BATCH  16384
#define XDIM   18
#define LATENT 16
#define NM     128
#define KDIM   4096
#define OUTF   64
#define KB     32

#define HS_STRIDE 264          // us; 528 B = 33 superbanks (odd mod 8) -> conflict-free b128
#define LDS_BYTES 99328        // wlds 65536 + hs 64*264*2 = 33792

typedef short s16x8 __attribute__((ext_vector_type(8)));
typedef float f32x16 __attribute__((ext_vector_type(16)));

__device__ __forceinline__ unsigned short f2bf(float f) {
    union { float f; unsigned u; } v; v.f = f;
    return (unsigned short)((v.u + 0x7FFFu + ((v.u >> 16) & 1u)) >> 16);
}

// ---------------------------------------------------------------------------
// Precompute (unchanged from passing round-2 kernel): W_eff / fc1_w into
// MFMA-fragment-layout bf16 buffers + b_eff.
// wfrag layout: [kc 0..255][ct 0..3][lane 0..63][8 bf16]
// f1frag layout: [jt 0..127][lane 0..63][8 bf16]
// ---------------------------------------------------------------------------
__global__ __launch_bounds__(128) void precompute_kernel(
    const float* __restrict__ x, const float* __restrict__ fc1_w,
    const float* __restrict__ fc2_w, const float* __restrict__ fc2_b,
    const float* __restrict__ dil, const float* __restrict__ shf,
    unsigned short* __restrict__ wfrag, unsigned short* __restrict__ f1frag,
    float* __restrict__ beff)
{
    const int tid = threadIdx.x;
    const int bid = blockIdx.x;
    if (bid < 512) {
        __shared__ float basis[KB];
        __shared__ float bred[32];
        if (tid < KB) {
            const float s   = x[(size_t)(BATCH - 1) * XDIM + 1];
            const float arg = s * dil[0] + shf[0];
            const float n   = 16.0f * (float)(tid & 15) / 15.0f;
            const float a   = arg * n;
            basis[tid] = (tid < 16) ? cosf(a) : sinf(a);
        }
        __syncthreads();
        const int m  = bid >> 2, kq = bid & 3;
        const int k8 = kq * 128 + tid;
        const int k  = k8 * 8;
        float acc[8] = {0.f,0.f,0.f,0.f,0.f,0.f,0.f,0.f};
        const float* src = fc2_w + (size_t)m * KB * KDIM + k;
        #pragma unroll 4
        for (int kb = 0; kb < KB; ++kb) {
            const float wgt = basis[kb];
            const float4 a = *(const float4*)(src + (size_t)kb * KDIM);
            const float4 b = *(const float4*)(src + (size_t)kb * KDIM + 4);
            acc[0] = fmaf(wgt, a.x, acc[0]); acc[1] = fmaf(wgt, a.y, acc[1]);
            acc[2] = fmaf(wgt, a.z, acc[2]); acc[3] = fmaf(wgt, a.w, acc[3]);
            acc[4] = fmaf(wgt, b.x, acc[4]); acc[5] = fmaf(wgt, b.y, acc[5]);
            acc[6] = fmaf(wgt, b.z, acc[6]); acc[7] = fmaf(wgt, b.w, acc[7]);
        }
        const int ct = m >> 5, coln = m & 31;
        const int kc = k8 >> 1, kg = k8 & 1;
        const int lane = kg * 32 + coln;
        unsigned short t[8];
        #pragma unroll
        for (int i = 0; i < 8; ++i) t[i] = f2bf(acc[i]);
        *(uint4*)(wfrag + ((size_t)(kc * 4 + ct) * 64 + lane) * 8) = *(const uint4*)t;
        if (kq == 0 && tid < 32) bred[tid] = basis[tid] * fc2_b[m * KB + tid];
        __syncthreads();
        if (kq == 0 && tid == 0) {
            float s = 0.f;
            #pragma unroll
            for (int i = 0; i < 32; ++i) s += bred[i];
            beff[m] = s;
        }
    } else {
        const int slot = (bid - 512) * 128 + tid;
        const int lane = slot & 63;
        const int jt   = slot >> 6;
        const int j    = jt * 32 + (lane & 31);
        const int kg   = lane >> 5;
        const float* src = fc1_w + (size_t)j * LATENT + kg * 8;
        const float4 a = *(const float4*)(src);
        const float4 b = *(const float4*)(src + 4);
        unsigned short t[8];
        t[0]=f2bf(a.x); t[1]=f2bf(a.y); t[2]=f2bf(a.z); t[3]=f2bf(a.w);
        t[4]=f2bf(b.x); t[5]=f2bf(b.y); t[6]=f2bf(b.z); t[7]=f2bf(b.w);
        *(uint4*)(f1frag + (size_t)slot * 8) = *(const uint4*)t;
    }
}

// ---------------------------------------------------------------------------
// Fused: 256 blocks x 1024 thr (16 waves). BM=64 rows.
// K chunked into 16 groups of 256. Per group:
//   MFMA phase: wave (rt=w&1, ks=w>>1) reads 2 A-frags from hs, 8 B-frags
//               from wlds, 8 MFMAs into acc[4] (one 32x32 tile per ct).
//   barrier; stage(g+1) via global_load_lds (64 KB) + hT(g+1) (16 MFMAs,
//   one per wave, jt_h=w&7, rt_h=w>>3) -> hs; barrier.
// Epilogue: sequential 8-pass K-split reduce into wfull (aliases wlds),
// + b_eff, then out = inp*w[:, :64] + w[:, 64:].
// ---------------------------------------------------------------------------
__global__ __launch_bounds__(1024, 4) void fused_kernel(
    const float* __restrict__ x, const float* __restrict__ fc1_b,
    const unsigned short* __restrict__ wfrag,
    const unsigned short* __restrict__ f1frag,
    const float* __restrict__ beff, float* __restrict__ out)
{
    extern __shared__ char smem[];
    unsigned short* wlds = (unsigned short*)smem;              // 32768 us
    unsigned short* hs   = (unsigned short*)(smem + 65536);    // 64 x 264 us
    float* wfull = (float*)smem;                               // epilogue alias

    const int tid  = threadIdx.x;
    const int w    = tid >> 6, l = tid & 63;
    const int l31  = l & 31,  lg = l >> 5;
    const int row0 = blockIdx.x * 64;
    const int rt   = w & 1,  ks   = w >> 1;   // main-phase roles
    const int jt_h = w & 7,  rt_h = w >> 3;   // hT-phase roles

    // z B-frag for hT: lane l holds z[rt_h*32 + l31][lg*8 + r] (loop-invariant)
    s16x8 zfrag;
    {
        const float* zp = x + (size_t)(row0 + rt_h * 32 + l31) * XDIM + 2 + lg * 8;
        #pragma unroll
        for (int q = 0; q < 4; ++q) {
            const float2 t = *(const float2*)(zp + q * 2);   // 8B-aligned always
            zfrag[2 * q]     = (short)f2bf(t.x);
            zfrag[2 * q + 1] = (short)f2bf(t.y);
        }
    }

    f32x16 acc[4];
    #pragma unroll
    for (int ct = 0; ct < 4; ++ct)
        #pragma unroll
        for (int i = 0; i < 16; ++i) acc[ct][i] = 0.0f;

    // stage group gg's B-frags (64 KB) into wlds via direct global->LDS DMA
    auto stage = [&](int gg) {
        const unsigned short* gsrc = wfrag + (size_t)gg * 32768;
        #pragma unroll
        for (int i = 0; i < 4; ++i) {
            __builtin_amdgcn_global_load_lds(
                (const __attribute__((address_space(1))) unsigned*)
                    (gsrc + ((size_t)(i * 1024 + tid)) * 8),
                (__attribute__((address_space(3))) unsigned*)
                    ((char*)wlds + w * 1024 + i * 16384),
                16, 0, 0);
        }
    };

    // compute h-tile for group gg (j range gg*256..+256) into hs
    auto do_hT = [&](int gg) {
        const uint4 fv = *(const uint4*)(f1frag + ((size_t)(gg * 8 + jt_h) * 64 + l) * 8);
        s16x8 afrag;
        #pragma unroll
        for (int i = 0; i < 4; ++i) {
            const unsigned u = ((const unsigned*)&fv)[i];
            afrag[2 * i]     = (short)(u & 0xFFFF);
            afrag[2 * i + 1] = (short)(u >> 16);
        }
        f32x16 hacc;
        #pragma unroll
        for (int i = 0; i < 16; ++i) hacc[i] = 0.0f;
        hacc = __builtin_amdgcn_mfma_f32_32x32x16_bf16(afrag, zfrag, hacc, 0, 0, 0);
        const float* bp = fc1_b + gg * 256 + jt_h * 32 + 4 * lg;
        unsigned short* hrow = hs + (size_t)(rt_h * 32 + l31) * HS_STRIDE + jt_h * 32 + 4 * lg;
        #pragma unroll
        for (int q = 0; q < 4; ++q) {
            const float4 bb = *(const float4*)(bp + 8 * q);
            const unsigned short t0 = f2bf(fmaxf(hacc[q * 4 + 0] + bb.x, 0.f));
            const unsigned short t1 = f2bf(fmaxf(hacc[q * 4 + 1] + bb.y, 0.f));
            const unsigned short t2 = f2bf(fmaxf(hacc[q * 4 + 2] + bb.z, 0.f));
            const unsigned short t3 = f2bf(fmaxf(hacc[q * 4 + 3] + bb.w, 0.f));
            uint2 u;
            u.x = (unsigned)t0 | ((unsigned)t1 << 16);
            u.y = (unsigned)t2 | ((unsigned)t3 << 16);
            *(uint2*)(hrow + 8 * q) = u;
        }
    };

    // prologue: group 0
    stage(0);
    do_hT(0);
    __syncthreads();

    for (int g = 0; g < 16; ++g) {
        // MFMA phase (reads wlds + hs of group g)
        #pragma unroll
        for (int kci = 0; kci < 2; ++kci) {
            const int kc = ks * 2 + kci;
            const s16x8 a = *(const s16x8*)(hs + (size_t)(rt * 32 + l31) * HS_STRIDE
                                               + kc * 16 + lg * 8);
            #pragma unroll
            for (int ct = 0; ct < 4; ++ct) {
                const s16x8 b = *(const s16x8*)(wlds + (size_t)(kc * 4 + ct) * 512 + l * 8);
                acc[ct] = __builtin_amdgcn_mfma_f32_32x32x16_bf16(a, b, acc[ct], 0, 0, 0);
            }
        }
        __syncthreads();
        if (g < 15) {
            stage(g + 1);     // issue early; latency hidden under hT
            do_hT(g + 1);
            __syncthreads();  // drains vmcnt (staged data) + lgkm (hs writes)
        }
    }

    // K-split reduce (deterministic sequential over ks) + b_eff
    #pragma unroll 1
    for (int p = 0; p < 8; ++p) {
        if (ks == p) {
            #pragma unroll
            for (int ct = 0; ct < 4; ++ct) {
                const float be = beff[ct * 32 + l31];
                #pragma unroll
                for (int r = 0; r < 16; ++r) {
                    const int rowl = (r & 3) + 8 * (r >> 2) + 4 * lg;
                    const int idx  = (rt * 32 + rowl) * NM + ct * 32 + l31;
                    wfull[idx] = (p == 0) ? (acc[ct][r] + be) : (wfull[idx] + acc[ct][r]);
                }
            }
        }
        __syncthreads();
    }

    // epilogue: out[b,o] = inp[b] * w[b,o] + w[b,64+o]
    {
        const int o = tid & 63, rg = tid >> 6;
        #pragma unroll
        for (int i = 0; i < 4; ++i) {
            const int r = rg * 4 + i;
            const float inp = x[(size_t)(row0 + r) * XDIM];
            out[(size_t)(row0 + r) * OUTF + o] =
                fmaf(inp, wfull[r * NM + o], wfull[r * NM + OUTF + o]);
        }
    }
}

// ---------------------------------------------------------------------------
extern "C" void kernel_launch(void* const* d_in, const int* in_sizes, int n_in,
                              void* d_out, int out_size, void* d_ws, size_t ws_size,
                              hipStream_t stream) {
    const float* x     = (const float*)d_in[0];
    const float* fc1_w = (const float*)d_in[1];
    const float* fc1_b = (const float*)d_in[2];
    const float* fc2_w = (const float*)d_in[3];
    const float* fc2_b = (const float*)d_in[4];
    const float* dil   = (const float*)d_in[5];
    const float* shf   = (const float*)d_in[6];
    float* out = (float*)d_out;

    unsigned short* wfrag  = (unsigned short*)d_ws;
    unsigned short* f1frag = wfrag + 524288;
    float*          beff   = (float*)(f1frag + 65536);

    hipFuncSetAttribute((const void*)fused_kernel,
                        hipFuncAttributeMaxDynamicSharedMemorySize, LDS_BYTES);

    precompute_kernel<<<576, 128, 0, stream>>>(x, fc1_w, fc2_w, fc2_b, dil, shf,
                                               wfrag, f1frag, beff);
    fused_kernel<<<BATCH / 64, 1024, LDS_BYTES, stream>>>(x, fc1_b, wfrag, f1frag,
                                                          beff, out);
}

// Round 4
// 75.401 us; speedup vs baseline: 3.9159x; 1.0401x over previous
//
#include <hip/hip_runtime.h>
#include <hip/hip_bf16.h>
#include <math.h>

#define BATCH  16384
#define XDIM   18
#define LATENT 16
#define NM     128
#define KDIM   4096
#define OUTF   64
#define KB     32

#define LDS_BYTES 98304   // wlds dbuf 2x32KB @0 | hs dbuf 2x16KB @64KB (wfull aliases @64KB)

typedef short s16x8 __attribute__((ext_vector_type(8)));
typedef float f32x16 __attribute__((ext_vector_type(16)));

__device__ __forceinline__ unsigned short f2bf(float f) {
    union { float f; unsigned u; } v; v.f = f;
    return (unsigned short)((v.u + 0x7FFFu + ((v.u >> 16) & 1u)) >> 16);
}
__device__ __forceinline__ unsigned pack_bf2(float a, float b) {
    __hip_bfloat162 h = __float22bfloat162_rn(make_float2(a, b));  // v_cvt_pk_bf16_f32
    return *(unsigned*)&h;
}

// ---------------------------------------------------------------------------
// Precompute (unchanged, proven): W_eff / fc1_w into MFMA-frag bf16 + b_eff.
// wfrag:  [kc 0..255][ct 0..3][lane 0..63][8 bf16]
// f1frag: [jt 0..127][lane 0..63][8 bf16]
// ---------------------------------------------------------------------------
__global__ __launch_bounds__(128) void precompute_kernel(
    const float* __restrict__ x, const float* __restrict__ fc1_w,
    const float* __restrict__ fc2_w, const float* __restrict__ fc2_b,
    const float* __restrict__ dil, const float* __restrict__ shf,
    unsigned short* __restrict__ wfrag, unsigned short* __restrict__ f1frag,
    float* __restrict__ beff)
{
    const int tid = threadIdx.x;
    const int bid = blockIdx.x;
    if (bid < 512) {
        __shared__ float basis[KB];
        __shared__ float bred[32];
        if (tid < KB) {
            const float s   = x[(size_t)(BATCH - 1) * XDIM + 1];
            const float arg = s * dil[0] + shf[0];
            const float n   = 16.0f * (float)(tid & 15) / 15.0f;
            const float a   = arg * n;
            basis[tid] = (tid < 16) ? cosf(a) : sinf(a);
        }
        __syncthreads();
        const int m  = bid >> 2, kq = bid & 3;
        const int k8 = kq * 128 + tid;
        const int k  = k8 * 8;
        float acc[8] = {0.f,0.f,0.f,0.f,0.f,0.f,0.f,0.f};
        const float* src = fc2_w + (size_t)m * KB * KDIM + k;
        #pragma unroll 4
        for (int kb = 0; kb < KB; ++kb) {
            const float wgt = basis[kb];
            const float4 a = *(const float4*)(src + (size_t)kb * KDIM);
            const float4 b = *(const float4*)(src + (size_t)kb * KDIM + 4);
            acc[0] = fmaf(wgt, a.x, acc[0]); acc[1] = fmaf(wgt, a.y, acc[1]);
            acc[2] = fmaf(wgt, a.z, acc[2]); acc[3] = fmaf(wgt, a.w, acc[3]);
            acc[4] = fmaf(wgt, b.x, acc[4]); acc[5] = fmaf(wgt, b.y, acc[5]);
            acc[6] = fmaf(wgt, b.z, acc[6]); acc[7] = fmaf(wgt, b.w, acc[7]);
        }
        const int ct = m >> 5, coln = m & 31;
        const int kc = k8 >> 1, kg = k8 & 1;
        const int lane = kg * 32 + coln;
        unsigned short t[8];
        #pragma unroll
        for (int i = 0; i < 8; ++i) t[i] = f2bf(acc[i]);
        *(uint4*)(wfrag + ((size_t)(kc * 4 + ct) * 64 + lane) * 8) = *(const uint4*)t;
        if (kq == 0 && tid < 32) bred[tid] = basis[tid] * fc2_b[m * KB + tid];
        __syncthreads();
        if (kq == 0 && tid == 0) {
            float s = 0.f;
            #pragma unroll
            for (int i = 0; i < 32; ++i) s += bred[i];
            beff[m] = s;
        }
    } else {
        const int slot = (bid - 512) * 128 + tid;
        const int lane = slot & 63;
        const int jt   = slot >> 6;
        const int j    = jt * 32 + (lane & 31);
        const int kg   = lane >> 5;
        const float* src = fc1_w + (size_t)j * LATENT + kg * 8;
        const float4 a = *(const float4*)(src);
        const float4 b = *(const float4*)(src + 4);
        unsigned short t[8];
        t[0]=f2bf(a.x); t[1]=f2bf(a.y); t[2]=f2bf(a.z); t[3]=f2bf(a.w);
        t[4]=f2bf(b.x); t[5]=f2bf(b.y); t[6]=f2bf(b.z); t[7]=f2bf(b.w);
        *(uint4*)(f1frag + (size_t)slot * 8) = *(const uint4*)t;
    }
}

// ---------------------------------------------------------------------------
// Fused: 256 blocks x 1024 thr (16 waves), BM=64 rows, K in 32 groups of 128.
// Double-buffered wlds + hs; ONE barrier per group. Per group g:
//   issue hT-loads(g+1) + stage(g+1)  [loads fly under compute]
//   main MFMA(g): wave (rt=w&1, ks=w>>1): 1 A-frag + 4 B-frags, 4 MFMAs
//   hT(g+1) compute (waves 0-7): bias-as-C mfma, relu, cvt_pk -> A-frag store
//   __syncthreads()   [drain happens AFTER compute covered the latency]
// h is stored directly in A-fragment layout -> all LDS ops conflict-free.
// Epilogue: sequential 8-pass K-split reduce + b_eff -> wfull; out epilogue.
// ---------------------------------------------------------------------------
__global__ __launch_bounds__(1024, 4) void fused_kernel(
    const float* __restrict__ x, const float* __restrict__ fc1_b,
    const unsigned short* __restrict__ wfrag,
    const unsigned short* __restrict__ f1frag,
    const float* __restrict__ beff, float* __restrict__ out)
{
    extern __shared__ char smem[];
    float* wfull = (float*)(smem + 65536);   // epilogue alias over hs dbuf (32 KB)

    const int tid  = threadIdx.x;
    const int w    = tid >> 6, l = tid & 63;
    const int l31  = l & 31,  lg = l >> 5;
    const int row0 = blockIdx.x * 64;
    const int rt   = w & 1,  ks   = w >> 1;   // main-phase role
    const int jt_h = w & 3,  rt_h = w >> 2;   // hT role (waves 0-7)
    const bool hwave = (w < 8);

    // z B-frag (hT): lane l holds z[rt_h*32 + l31][lg*8 + r]  (loop-invariant)
    s16x8 zfrag;
    #pragma unroll
    for (int i = 0; i < 8; ++i) zfrag[i] = 0;
    if (hwave) {
        const float* zp = x + (size_t)(row0 + rt_h * 32 + l31) * XDIM + 2 + lg * 8;
        #pragma unroll
        for (int q = 0; q < 4; ++q) {
            const float2 t = *(const float2*)(zp + q * 2);
            ((unsigned*)&zfrag)[q] = pack_bf2(t.x, t.y);
        }
    }

    f32x16 acc[4];
    #pragma unroll
    for (int ct = 0; ct < 4; ++ct)
        #pragma unroll
        for (int i = 0; i < 16; ++i) acc[ct][i] = 0.0f;

    // stage group gg's 32 KB of B-frags into wlds buf (gg&1) via global->LDS DMA
    auto stage = [&](int gg) {
        const unsigned short* gsrc = wfrag + (size_t)gg * 16384;
        char* dstb = smem + (gg & 1) * 32768 + w * 1024;   // wave-uniform base
        #pragma unroll
        for (int it = 0; it < 2; ++it) {
            __builtin_amdgcn_global_load_lds(
                (const __attribute__((address_space(1))) unsigned*)
                    (gsrc + ((size_t)(it * 1024 + tid)) * 8),
                (__attribute__((address_space(3))) unsigned*)(dstb + it * 16384),
                16, 0, 0);
        }
    };

    uint4 fv; float4 fb0, fb1, fb2, fb3;

    auto hT_load = [&](int gg) {
        fv = *(const uint4*)(f1frag + ((size_t)((gg * 4 + jt_h) * 64 + l)) * 8);
        const float* bp = fc1_b + gg * 128 + jt_h * 32 + 4 * lg;
        fb0 = *(const float4*)(bp);
        fb1 = *(const float4*)(bp + 8);
        fb2 = *(const float4*)(bp + 16);
        fb3 = *(const float4*)(bp + 24);
    };

    auto hT_compute = [&](int gg) {
        f32x16 hacc;
        hacc[0]=fb0.x;  hacc[1]=fb0.y;  hacc[2]=fb0.z;  hacc[3]=fb0.w;
        hacc[4]=fb1.x;  hacc[5]=fb1.y;  hacc[6]=fb1.z;  hacc[7]=fb1.w;
        hacc[8]=fb2.x;  hacc[9]=fb2.y;  hacc[10]=fb2.z; hacc[11]=fb2.w;
        hacc[12]=fb3.x; hacc[13]=fb3.y; hacc[14]=fb3.z; hacc[15]=fb3.w;
        const s16x8 afrag = *(const s16x8*)&fv;          // bf16 already in order
        hacc = __builtin_amdgcn_mfma_f32_32x32x16_bf16(afrag, zfrag, hacc, 0, 0, 0);
        // C: col=l31 (batch), row=(r&3)+8*(r>>2)+4*lg (j within 32-tile).
        // Store straight into A-frag positions: element (batch=l31, k=lg_a*8+r_a)
        // at frag us offset (lg_a*32 + l31)*8 + r_a, frag = jt_h*2 + (q>>1).
        unsigned short* hb = (unsigned short*)(smem + 65536 + (gg & 1) * 16384);
        #pragma unroll
        for (int q = 0; q < 4; ++q) {
            uint2 u;
            u.x = pack_bf2(fmaxf(hacc[4*q+0], 0.f), fmaxf(hacc[4*q+1], 0.f));
            u.y = pack_bf2(fmaxf(hacc[4*q+2], 0.f), fmaxf(hacc[4*q+3], 0.f));
            *(uint2*)(hb + ((size_t)((rt_h * 8 + jt_h * 2 + (q >> 1)) * 64
                                     + (q & 1) * 32 + l31)) * 8 + 4 * lg) = u;
        }
    };

    // prologue: group 0
    stage(0);
    if (hwave) { hT_load(0); hT_compute(0); }
    __syncthreads();

    #pragma unroll 2
    for (int g = 0; g < 32; ++g) {
        const bool pre = (g < 31);
        if (pre) {
            if (hwave) hT_load(g + 1);   // issue early
            stage(g + 1);                // issue early
        }
        // main MFMA phase on buffers g&1
        {
            const unsigned short* wl = (const unsigned short*)(smem + (g & 1) * 32768);
            const unsigned short* hs = (const unsigned short*)(smem + 65536 + (g & 1) * 16384);
            const s16x8 a = *(const s16x8*)(hs + ((size_t)((rt * 8 + ks) * 64 + l)) * 8);
            #pragma unroll
            for (int ct = 0; ct < 4; ++ct) {
                const s16x8 b = *(const s16x8*)(wl + ((size_t)((ks * 4 + ct) * 512)) + l * 8);
                acc[ct] = __builtin_amdgcn_mfma_f32_32x32x16_bf16(a, b, acc[ct], 0, 0, 0);
            }
        }
        if (pre && hwave) hT_compute(g + 1);
        __syncthreads();
    }

    // K-split reduce (sequential over ks, deterministic) + b_eff
    #pragma unroll 1
    for (int p = 0; p < 8; ++p) {
        if (ks == p) {
            #pragma unroll
            for (int ct = 0; ct < 4; ++ct) {
                const float be = beff[ct * 32 + l31];
                #pragma unroll
                for (int r = 0; r < 16; ++r) {
                    const int rowl = (r & 3) + 8 * (r >> 2) + 4 * lg;
                    const int idx  = (rt * 32 + rowl) * NM + ct * 32 + l31;
                    wfull[idx] = (p == 0) ? (acc[ct][r] + be) : (wfull[idx] + acc[ct][r]);
                }
            }
        }
        __syncthreads();
    }

    // out[b,o] = inp[b] * w[b,o] + w[b,64+o]
    {
        const int o = tid & 63, rg = tid >> 6;
        #pragma unroll
        for (int i = 0; i < 4; ++i) {
            const int r = rg * 4 + i;
            const float inp = x[(size_t)(row0 + r) * XDIM];
            out[(size_t)(row0 + r) * OUTF + o] =
                fmaf(inp, wfull[r * NM + o], wfull[r * NM + OUTF + o]);
        }
    }
}

// ---------------------------------------------------------------------------
extern "C" void kernel_launch(void* const* d_in, const int* in_sizes, int n_in,
                              void* d_out, int out_size, void* d_ws, size_t ws_size,
                              hipStream_t stream) {
    const float* x     = (const float*)d_in[0];
    const float* fc1_w = (const float*)d_in[1];
    const float* fc1_b = (const float*)d_in[2];
    const float* fc2_w = (const float*)d_in[3];
    const float* fc2_b = (const float*)d_in[4];
    const float* dil   = (const float*)d_in[5];
    const float* shf   = (const float*)d_in[6];
    float* out = (float*)d_out;

    unsigned short* wfrag  = (unsigned short*)d_ws;
    unsigned short* f1frag = wfrag + 524288;
    float*          beff   = (float*)(f1frag + 65536);

    hipFuncSetAttribute((const void*)fused_kernel,
                        hipFuncAttributeMaxDynamicSharedMemorySize, LDS_BYTES);

    precompute_kernel<<<576, 128, 0, stream>>>(x, fc1_w, fc2_w, fc2_b, dil, shf,
                                               wfrag, f1frag, beff);
    fused_kernel<<<BATCH / 64, 1024, LDS_BYTES, stream>>>(x, fc1_b, wfrag, f1frag,
                                                          beff, out);
}

// Round 5
// 74.003 us; speedup vs baseline: 3.9898x; 1.0189x over previous
//
#include <hip/hip_runtime.h>
#include <hip/hip_bf16.h>
#include <math.h>

#define BATCH  16384
#define XDIM   18
#define LATENT 16
#define NM     128
#define KDIM   4096
#define OUTF   64
#define KB     32

typedef short s16x8 __attribute__((ext_vector_type(8)));
typedef float f32x16 __attribute__((ext_vector_type(16)));

__device__ __forceinline__ unsigned short f2bf(float f) {
    union { float f; unsigned u; } v; v.f = f;
    return (unsigned short)((v.u + 0x7FFFu + ((v.u >> 16) & 1u)) >> 16);
}
__device__ __forceinline__ unsigned pack_bf2(float a, float b) {
    __hip_bfloat162 h = __float22bfloat162_rn(make_float2(a, b));  // v_cvt_pk_bf16_f32
    return *(unsigned*)&h;
}
// swap bits 2 and 3 (the sigma' map: hacc C-row -> k index)
__device__ __forceinline__ int swap23(int m) {
    return (m & ~12) | ((m & 4) << 1) | ((m & 8) >> 1);
}

// ---------------------------------------------------------------------------
// Precompute: W_eff -> wfrag (B-frag layout), fc1_w -> f1frag (A-frag layout,
// columns sigma-permuted), fc1_b -> bh (hacc/C-layout, sigma-permuted), b_eff.
//   blocks 0..511   : wfrag + beff
//   blocks 512..575 : f1frag (j = jt*32 + swap23(l31))
//   block  576      : bh[jt][lg*16 + r] = fc1_b[jt*32 + swap23(crow(r,lg))]
// wfrag:  [kc 0..255][ct 0..3][lane 0..63][8 bf16]
// f1frag: [jt 0..127][lane 0..63][8 bf16]
// ---------------------------------------------------------------------------
__global__ __launch_bounds__(128) void precompute_kernel(
    const float* __restrict__ x, const float* __restrict__ fc1_w,
    const float* __restrict__ fc1_b, const float* __restrict__ fc2_w,
    const float* __restrict__ fc2_b, const float* __restrict__ dil,
    const float* __restrict__ shf, unsigned short* __restrict__ wfrag,
    unsigned short* __restrict__ f1frag, float* __restrict__ bh,
    float* __restrict__ beff)
{
    const int tid = threadIdx.x;
    const int bid = blockIdx.x;
    if (bid < 512) {
        __shared__ float basis[KB];
        __shared__ float bred[32];
        if (tid < KB) {
            const float s   = x[(size_t)(BATCH - 1) * XDIM + 1];
            const float arg = s * dil[0] + shf[0];
            const float n   = 16.0f * (float)(tid & 15) / 15.0f;
            const float a   = arg * n;
            basis[tid] = (tid < 16) ? cosf(a) : sinf(a);
        }
        __syncthreads();
        const int m  = bid >> 2, kq = bid & 3;
        const int k8 = kq * 128 + tid;
        const int k  = k8 * 8;
        float acc[8] = {0.f,0.f,0.f,0.f,0.f,0.f,0.f,0.f};
        const float* src = fc2_w + (size_t)m * KB * KDIM + k;
        #pragma unroll 4
        for (int kb = 0; kb < KB; ++kb) {
            const float wgt = basis[kb];
            const float4 a = *(const float4*)(src + (size_t)kb * KDIM);
            const float4 b = *(const float4*)(src + (size_t)kb * KDIM + 4);
            acc[0] = fmaf(wgt, a.x, acc[0]); acc[1] = fmaf(wgt, a.y, acc[1]);
            acc[2] = fmaf(wgt, a.z, acc[2]); acc[3] = fmaf(wgt, a.w, acc[3]);
            acc[4] = fmaf(wgt, b.x, acc[4]); acc[5] = fmaf(wgt, b.y, acc[5]);
            acc[6] = fmaf(wgt, b.z, acc[6]); acc[7] = fmaf(wgt, b.w, acc[7]);
        }
        const int ct = m >> 5, coln = m & 31;
        const int kc = k8 >> 1, kg = k8 & 1;
        const int lane = kg * 32 + coln;
        unsigned short t[8];
        #pragma unroll
        for (int i = 0; i < 8; ++i) t[i] = f2bf(acc[i]);
        *(uint4*)(wfrag + ((size_t)(kc * 4 + ct) * 64 + lane) * 8) = *(const uint4*)t;
        if (kq == 0 && tid < 32) bred[tid] = basis[tid] * fc2_b[m * KB + tid];
        __syncthreads();
        if (kq == 0 && tid == 0) {
            float s = 0.f;
            #pragma unroll
            for (int i = 0; i < 32; ++i) s += bred[i];
            beff[m] = s;
        }
    } else if (bid < 576) {
        const int slot = (bid - 512) * 128 + tid;   // 0..8191
        const int lane = slot & 63;
        const int jt   = slot >> 6;
        const int j    = jt * 32 + swap23(lane & 31);   // sigma-permuted column
        const int kg   = lane >> 5;
        const float* src = fc1_w + (size_t)j * LATENT + kg * 8;
        const float4 a = *(const float4*)(src);
        const float4 b = *(const float4*)(src + 4);
        unsigned short t[8];
        t[0]=f2bf(a.x); t[1]=f2bf(a.y); t[2]=f2bf(a.z); t[3]=f2bf(a.w);
        t[4]=f2bf(b.x); t[5]=f2bf(b.y); t[6]=f2bf(b.z); t[7]=f2bf(b.w);
        *(uint4*)(f1frag + (size_t)slot * 8) = *(const uint4*)t;
    } else {
        // bias in hacc layout: bh[jt*32 + lg*16 + r] = fc1_b[jt*32 + swap23(crow)]
        const int jt = tid;   // 0..127
        #pragma unroll
        for (int mp = 0; mp < 32; ++mp) {
            const int lg = mp >> 4, r = mp & 15;
            const int crow = (r & 3) + 8 * (r >> 2) + 4 * lg;
            bh[jt * 32 + mp] = fc1_b[jt * 32 + swap23(crow)];
        }
    }
}

// ---------------------------------------------------------------------------
// Fused: 256 blocks x 1024 thr (16 waves), BM=64 rows. NO LDS / NO barriers
// in the main loop. Wave = (rt, ct, kh): rt picks 32 rows, ct picks 32 output
// cols, kh picks K-half (2048 k). Per j-tile (32 k): load f1frag A-frag +
// bias(C) + 2 B-frags from L2; hT mfma -> relu+pack -> 2 main mfma into acc.
// sigma-permuted f1frag makes A-frag(kc) = pack(hacc[0..7] / [8..15]) with
// no cross-lane ops. Tail: 2-barrier deterministic kh-reduce + epilogue.
// ---------------------------------------------------------------------------
__global__ __launch_bounds__(1024, 4) void fused_kernel(
    const float* __restrict__ x,
    const unsigned short* __restrict__ wfrag,
    const unsigned short* __restrict__ f1frag,
    const float* __restrict__ bh,
    const float* __restrict__ beff, float* __restrict__ out)
{
    __shared__ float wfull[64 * NM];   // 32 KB

    const int tid = threadIdx.x;
    const int w   = tid >> 6, l = tid & 63;
    const int l31 = l & 31,  lg = l >> 5;
    const int row0 = blockIdx.x * 64;
    const int rt = w & 1, ct = (w >> 1) & 3, kh = w >> 3;

    // zfrag: lane l holds z[row0 + rt*32 + l31][lg*8 + r]  (loop-invariant)
    s16x8 zfrag;
    {
        const float* zp = x + (size_t)(row0 + rt * 32 + l31) * XDIM + 2 + lg * 8;
        #pragma unroll
        for (int q = 0; q < 4; ++q) {
            const float2 t = *(const float2*)(zp + 2 * q);
            ((unsigned*)&zfrag)[q] = pack_bf2(t.x, t.y);
        }
    }

    f32x16 acc;
    #pragma unroll
    for (int i = 0; i < 16; ++i) acc[i] = 0.0f;

    const unsigned short* fvp = f1frag + ((size_t)(kh * 64) * 64 + l) * 8;
    const float*          bhp = bh + (size_t)(kh * 64) * 32 + lg * 16;
    const unsigned short* bp  = wfrag + ((size_t)(kh * 128) * 4 + ct) * 512 + l * 8;

    #pragma unroll 2
    for (int t = 0; t < 64; ++t) {
        const uint4  fv = *(const uint4*)(fvp);
        const float4 c0 = *(const float4*)(bhp);
        const float4 c1 = *(const float4*)(bhp + 4);
        const float4 c2 = *(const float4*)(bhp + 8);
        const float4 c3 = *(const float4*)(bhp + 12);
        const s16x8  B0 = *(const s16x8*)(bp);
        const s16x8  B1 = *(const s16x8*)(bp + 4 * 512);
        fvp += 64 * 8;
        bhp += 32;
        bp  += 8 * 512;

        f32x16 hc;
        hc[0]=c0.x;  hc[1]=c0.y;  hc[2]=c0.z;  hc[3]=c0.w;
        hc[4]=c1.x;  hc[5]=c1.y;  hc[6]=c1.z;  hc[7]=c1.w;
        hc[8]=c2.x;  hc[9]=c2.y;  hc[10]=c2.z; hc[11]=c2.w;
        hc[12]=c3.x; hc[13]=c3.y; hc[14]=c3.z; hc[15]=c3.w;
        hc = __builtin_amdgcn_mfma_f32_32x32x16_bf16(*(const s16x8*)&fv, zfrag, hc, 0, 0, 0);

        unsigned a0[4], a1[4];
        #pragma unroll
        for (int q = 0; q < 4; ++q) {
            a0[q] = pack_bf2(fmaxf(hc[2*q],   0.f), fmaxf(hc[2*q+1],   0.f));
            a1[q] = pack_bf2(fmaxf(hc[8+2*q], 0.f), fmaxf(hc[8+2*q+1], 0.f));
        }
        acc = __builtin_amdgcn_mfma_f32_32x32x16_bf16(*(const s16x8*)a0, B0, acc, 0, 0, 0);
        acc = __builtin_amdgcn_mfma_f32_32x32x16_bf16(*(const s16x8*)a1, B1, acc, 0, 0, 0);
    }

    // deterministic kh-reduce through LDS (2 barriers total)
    if (kh == 1) {
        #pragma unroll
        for (int r = 0; r < 16; ++r) {
            const int rowl = (r & 3) + 8 * (r >> 2) + 4 * lg;
            wfull[(rt * 32 + rowl) * NM + ct * 32 + l31] = acc[r];
        }
    }
    __syncthreads();
    if (kh == 0) {
        const float be = beff[ct * 32 + l31];
        #pragma unroll
        for (int r = 0; r < 16; ++r) {
            const int rowl = (r & 3) + 8 * (r >> 2) + 4 * lg;
            const int idx  = (rt * 32 + rowl) * NM + ct * 32 + l31;
            wfull[idx] = wfull[idx] + acc[r] + be;
        }
    }
    __syncthreads();

    // out[b,o] = inp[b] * w[b,o] + w[b,64+o]
    {
        const int o = tid & 63, rg = tid >> 6;
        #pragma unroll
        for (int i = 0; i < 4; ++i) {
            const int r = rg * 4 + i;
            const float inp = x[(size_t)(row0 + r) * XDIM];
            out[(size_t)(row0 + r) * OUTF + o] =
                fmaf(inp, wfull[r * NM + o], wfull[r * NM + OUTF + o]);
        }
    }
}

// ---------------------------------------------------------------------------
extern "C" void kernel_launch(void* const* d_in, const int* in_sizes, int n_in,
                              void* d_out, int out_size, void* d_ws, size_t ws_size,
                              hipStream_t stream) {
    const float* x     = (const float*)d_in[0];
    const float* fc1_w = (const float*)d_in[1];
    const float* fc1_b = (const float*)d_in[2];
    const float* fc2_w = (const float*)d_in[3];
    const float* fc2_b = (const float*)d_in[4];
    const float* dil   = (const float*)d_in[5];
    const float* shf   = (const float*)d_in[6];
    float* out = (float*)d_out;

    // ws: wfrag 1 MB | f1frag 128 KB | beff 512 B | bh 16 KB
    unsigned short* wfrag  = (unsigned short*)d_ws;
    unsigned short* f1frag = wfrag + 524288;
    float*          beff   = (float*)(f1frag + 65536);
    float*          bh     = beff + NM;

    precompute_kernel<<<577, 128, 0, stream>>>(x, fc1_w, fc1_b, fc2_w, fc2_b,
                                               dil, shf, wfrag, f1frag, bh, beff);
    fused_kernel<<<BATCH / 64, 1024, 0, stream>>>(x, wfrag, f1frag, bh, beff, out);
}